// Round 6
// baseline (144.121 us; speedup 1.0000x reference)
//
#include <hip/hip_runtime.h>
#include <hip/hip_bf16.h>
#include <math.h>

#define C_CH 256

typedef const __attribute__((address_space(1))) void* gas_t;
typedef __attribute__((address_space(3))) void* las_t;

// ---------------------------------------------------------------------------
// Transpose all 4 FPN levels from fp32 (C,H,W) to bf16 (H*W, C) in d_ws.
// R6: 2 tiles per block, software-pipelined with COUNTED vmcnt (guide T3/T4):
//   issue 4 gload_lds/wave (tile A), issue 4 (tile B),
//   s_waitcnt vmcnt(4)  -> A landed, B still in flight
//   s_barrier, store A  -> global stores overlap B's DMA
//   s_waitcnt vmcnt(4)  -> B landed (oldest 4 of {4 B-loads, 4 A-stores})
//   s_barrier, store B.
// No __syncthreads => no vmcnt(0) drain window (the ~900-cy dead stall per
// block in R5). Raw s_barrier + asm waitcnt per the verified 8-phase template;
// sched_barrier(0) fences per guide rule #18. LDS 32 KB -> 5 blocks/CU
// (Little's law: ~9 KB in flight/CU saturates HBM; 20 waves x 4 KB is ample).
// Tile geometry, swizzle, and store pattern identical to R5 (proven).
// ---------------------------------------------------------------------------
struct TI { const float* src; __hip_bfloat16* dst; int S; };

__device__ __forceinline__ TI tinfo(int b, const float* f0, const float* f1,
                                    const float* f2, const float* f3,
                                    __hip_bfloat16* tf) {
  TI ti; int lg; size_t dstoff; int sb;
  if (b < 4096)      { ti.src = f0; ti.S = 65536; lg = 10; dstoff = 0;     sb = b; }
  else if (b < 5120) { ti.src = f1; ti.S = 16384; lg = 8;  dstoff = 65536; sb = b - 4096; }
  else if (b < 5376) { ti.src = f2; ti.S = 4096;  lg = 6;  dstoff = 81920; sb = b - 5120; }
  else               { ti.src = f3; ti.S = 1024;  lg = 4;  dstoff = 86016; sb = b - 5376; }
  const int nsp_m1 = (1 << lg) - 1;
  const int s0 = (sb & nsp_m1) * 64;
  const int c0 = (sb >> lg) * 64;
  ti.src += (size_t)c0 * ti.S + s0;
  ti.dst = tf + (dstoff + (size_t)s0) * C_CH + c0;
  return ti;
}

__device__ __forceinline__ void t_load(const TI& ti, float* tile, int wv,
                                       int lane) {
  // lane covers channel row c = 4*wv + 16*j + (lane>>4); global column
  // pre-swizzled by wave-uniform K = c>>2 = wv + 4*j so LDS stays linear
  // while the logical layout is XOR-swizzled for the read phase (m173/T2).
  #pragma unroll
  for (int j = 0; j < 4; ++j) {
    const int c = 4 * wv + 16 * j + (lane >> 4);
    const int K = (wv + 4 * j) & 15;
    const int slot = (lane & 15) ^ K;
    const float* g = ti.src + (size_t)c * ti.S + slot * 4;
    float* l = &tile[(4 * wv + 16 * j) * 64];  // wave-uniform base (m104)
    __builtin_amdgcn_global_load_lds((gas_t)g, (las_t)l, 16, 0, 0);
  }
}

__device__ __forceinline__ void t_store(const TI& ti, const float* tile,
                                        int t) {
  const int spl = t >> 4;   // 0..15
  const int i16 = t & 15;
  const int c4 = i16 * 4;   // 0..60
  #pragma unroll
  for (int j = 0; j < 4; ++j) {
    const int sp = spl + 16 * j;
    const int sl = sp >> 2;  // logical 16B slot
    union { ushort4 u; __hip_bfloat16 h[4]; } p;
    #pragma unroll
    for (int k = 0; k < 4; ++k) {
      const int c = c4 + k;  // c>>2 == i16
      p.h[k] = __float2bfloat16(tile[c * 64 + ((sl ^ i16) << 2) + (sp & 3)]);
    }
    *(ushort4*)(ti.dst + (size_t)sp * C_CH + c4) = p.u;
  }
}

__global__ __launch_bounds__(256) void transpose_all(
    const float* __restrict__ f0, const float* __restrict__ f1,
    const float* __restrict__ f2, const float* __restrict__ f3,
    __hip_bfloat16* __restrict__ tf) {
  __shared__ float tile[2][64 * 64];  // 32 KB, linear (swizzle via global)
  const int b = blockIdx.x;  // 2720 blocks x 2 tiles (level bounds all even)
  const int t = threadIdx.x;
  const int lane = t & 63;
  const int wv = t >> 6;  // wave 0..3

  const TI ta = tinfo(2 * b,     f0, f1, f2, f3, tf);
  const TI tb = tinfo(2 * b + 1, f0, f1, f2, f3, tf);

  t_load(ta, tile[0], wv, lane);            // vm: 4/wave
  __builtin_amdgcn_sched_barrier(0);        // keep A-before-B issue order
  t_load(tb, tile[1], wv, lane);            // vm: 8/wave
  __builtin_amdgcn_sched_barrier(0);

  asm volatile("s_waitcnt vmcnt(4)" ::: "memory");  // A landed (in-order)
  __builtin_amdgcn_s_barrier();                      // block-wide A ready
  __builtin_amdgcn_sched_barrier(0);
  t_store(ta, tile[0], t);                  // stores overlap B's DMA

  asm volatile("s_waitcnt vmcnt(4)" ::: "memory");  // oldest 4 = B loads done
  __builtin_amdgcn_s_barrier();                      // block-wide B ready
  __builtin_amdgcn_sched_barrier(0);
  t_store(tb, tile[1], t);
}

__device__ __forceinline__ float bfu(unsigned short s) {
  union { unsigned u; float f; } v;
  v.u = (unsigned)s << 16;
  return v.f;
}

// ---------------------------------------------------------------------------
// ROI Align + 2x2 max pool, transposed bf16 path. (R4 body, unchanged —
// channel-split 2x TLP; kept verbatim for clean attribution.)
// ---------------------------------------------------------------------------
__global__ __launch_bounds__(512, 8) void roi_bf16(
    const unsigned short* __restrict__ tf,
    const float* __restrict__ proposals, float* __restrict__ out) {
  __shared__ int xo0[14], xo1[14], yo0[14], yo1[14];
  __shared__ float wxa[14], wxb[14], wya[14], wyb[14];
  __shared__ float obuf[49 * 128];  // 24.5 KB, XOR-swizzled 8-B slots

  const int n = blockIdx.x >> 1;
  const int half = blockIdx.x & 1;
  const int t = threadIdx.x;
  const int lane = t & 63;
  const int w = t >> 6;  // wave id 0..7

  const float px1 = proposals[n * 4 + 0];
  const float py1 = proposals[n * 4 + 1];
  const float px2 = proposals[n * 4 + 2];
  const float py2 = proposals[n * 4 + 3];
  float lt = 2.0f + log2f(sqrtf((px2 - px1) * (py2 - py1)) / 224.0f);
  int lvl = (int)floorf(lt);
  lvl = lvl < 0 ? 0 : (lvl > 3 ? 3 : lvl);

  const float scales[4] = {0.25f, 0.125f, 0.0625f, 0.03125f};
  const int sizes[4] = {256, 128, 64, 32};
  const int offs[4] = {0, 65536, 81920, 86016};
  const float sc = scales[lvl];
  const int sz = sizes[lvl];

  const float bx1 = px1 * sc, by1 = py1 * sc;
  const float w_unit = ((px2 - px1) * sc / 7.0f) * 0.5f;
  const float h_unit = ((py2 - py1) * sc / 7.0f) * 0.5f;

  if (t < 14) {
    const int i = t;
    float x = bx1 + ((float)i + 0.5f) * w_unit;
    int xf = (int)floorf(x);
    int x0 = min(max(xf, 0), sz - 1);
    int x1 = min(max(xf + 1, 0), sz - 1);
    wxa[i] = (float)x1 - x;  // matches ref incl. clipped extrapolation
    wxb[i] = x - (float)x0;
    xo0[i] = x0 * C_CH;
    xo1[i] = x1 * C_CH;
  } else if (t >= 64 && t < 78) {
    const int i = t - 64;
    float y = by1 + ((float)i + 0.5f) * h_unit;
    int yf = (int)floorf(y);
    int y0 = min(max(yf, 0), sz - 1);
    int y1 = min(max(yf + 1, 0), sz - 1);
    wya[i] = (float)y1 - y;
    wyb[i] = y - (float)y0;
    yo0[i] = y0 * sz * C_CH;
    yo1[i] = y1 * sz * C_CH;
  }
  __syncthreads();

  if (w < 7) {  // wave-uniform: waves 0-6 compute, wave 7 only helps store
    const int oh = w;
    const int gy0 = 2 * oh, gy1 = 2 * oh + 1;
    // lane covers channels half*128 + lane*2 (+0,+1)
    const unsigned short* base =
        tf + (size_t)offs[lvl] * C_CH + half * 128 + lane * 2;
    const unsigned short* r00 = base + yo0[gy0];
    const unsigned short* r01 = base + yo1[gy0];
    const unsigned short* r10 = base + yo0[gy1];
    const unsigned short* r11 = base + yo1[gy1];
    const float wy0a = wya[gy0], wy0b = wyb[gy0];
    const float wy1a = wya[gy1], wy1b = wyb[gy1];

    float mm[7][2];
    #pragma unroll
    for (int j = 0; j < 7; ++j) {
      mm[j][0] = -INFINITY;
      mm[j][1] = -INFINITY;
    }

    // Software-pipelined gather: prefetch gx+1 while computing gx.
    ushort2 nA0, nA1, nB0, nB1, nC0, nC1, nD0, nD1;
    {
      const int xa = xo0[0], xb = xo1[0];
      nA0 = *(const ushort2*)(r00 + xa);
      nA1 = *(const ushort2*)(r00 + xb);
      nB0 = *(const ushort2*)(r01 + xa);
      nB1 = *(const ushort2*)(r01 + xb);
      nC0 = *(const ushort2*)(r10 + xa);
      nC1 = *(const ushort2*)(r10 + xb);
      nD0 = *(const ushort2*)(r11 + xa);
      nD1 = *(const ushort2*)(r11 + xb);
    }
    #pragma unroll
    for (int gx = 0; gx < 14; ++gx) {
      const ushort2 A0 = nA0, A1 = nA1, B0 = nB0, B1 = nB1;
      const ushort2 C0 = nC0, C1 = nC1, D0 = nD0, D1 = nD1;
      if (gx < 13) {  // compile-time (fully unrolled)
        const int xa = xo0[gx + 1], xb = xo1[gx + 1];
        nA0 = *(const ushort2*)(r00 + xa);
        nA1 = *(const ushort2*)(r00 + xb);
        nB0 = *(const ushort2*)(r01 + xa);
        nB1 = *(const ushort2*)(r01 + xb);
        nC0 = *(const ushort2*)(r10 + xa);
        nC1 = *(const ushort2*)(r10 + xb);
        nD0 = *(const ushort2*)(r11 + xa);
        nD1 = *(const ushort2*)(r11 + xb);
      }
      const float fa = wxa[gx], fb = wxb[gx];
      const int j = gx >> 1;
      const unsigned short* a0 = (const unsigned short*)&A0;
      const unsigned short* a1 = (const unsigned short*)&A1;
      const unsigned short* b0 = (const unsigned short*)&B0;
      const unsigned short* b1 = (const unsigned short*)&B1;
      const unsigned short* c0 = (const unsigned short*)&C0;
      const unsigned short* c1 = (const unsigned short*)&C1;
      const unsigned short* d0 = (const unsigned short*)&D0;
      const unsigned short* d1 = (const unsigned short*)&D1;
      #pragma unroll
      for (int k = 0; k < 2; ++k) {
        const float h00 = fa * bfu(a0[k]) + fb * bfu(a1[k]);
        const float h01 = fa * bfu(b0[k]) + fb * bfu(b1[k]);
        const float va = wy0a * h00 + wy0b * h01;
        const float h10 = fa * bfu(c0[k]) + fb * bfu(c1[k]);
        const float h11 = fa * bfu(d0[k]) + fb * bfu(d1[k]);
        const float vb = wy1a * h10 + wy1b * h11;
        mm[j][k] = fmaxf(mm[j][k], fmaxf(va, vb));
      }
    }

    // Stage: obuf row p = oh*7+ow, 8-B slot (lane^p)&63 holds local channels
    // (2*lane, 2*lane+1). XOR keeps both write (float2, permutation -> exact
    // 2-way, free) and the epilogue's p-striding reads spread across banks.
    #pragma unroll
    for (int ow = 0; ow < 7; ++ow) {
      const int p = oh * 7 + ow;
      float2 v = make_float2(mm[ow][0], mm[ow][1]);
      *(float2*)&obuf[p * 128 + ((lane ^ p) & 63) * 2] = v;
    }
  }
  __syncthreads();

  // Contiguous coalesced block store of this half's 25 KB:
  // out[n*12544 + half*6272 + i], i = c_local*49 + p.
  float* ob = out + (size_t)n * (C_CH * 49) + half * (128 * 49);
  for (int i = t; i < 128 * 49; i += 512) {
    const unsigned cl = (unsigned)i / 49u;
    const unsigned p = (unsigned)i - cl * 49u;
    const unsigned q = ((cl >> 1) ^ p) & 63u;
    ob[i] = obuf[p * 128 + q * 2 + (cl & 1)];
  }
}

// ---------------------------------------------------------------------------
// Fallback (no workspace): direct (C,H,W) reads. Correctness-only path.
// ---------------------------------------------------------------------------
__global__ __launch_bounds__(64) void roi_fallback(
    const float* __restrict__ f0, const float* __restrict__ f1,
    const float* __restrict__ f2, const float* __restrict__ f3,
    const float* __restrict__ proposals, float* __restrict__ out) {
  __shared__ int xo0[14], xo1[14], yo0[14], yo1[14];
  __shared__ float wxa[14], wxb[14], wya[14], wyb[14];
  const int n = blockIdx.x;
  const int cblk = blockIdx.y;
  const int lane = threadIdx.x;
  const int c = cblk * 64 + lane;
  const float px1 = proposals[n * 4 + 0];
  const float py1 = proposals[n * 4 + 1];
  const float px2 = proposals[n * 4 + 2];
  const float py2 = proposals[n * 4 + 3];
  float lt = 2.0f + log2f(sqrtf((px2 - px1) * (py2 - py1)) / 224.0f);
  int lvl = (int)floorf(lt);
  lvl = lvl < 0 ? 0 : (lvl > 3 ? 3 : lvl);
  const float scales[4] = {0.25f, 0.125f, 0.0625f, 0.03125f};
  const int sizes[4] = {256, 128, 64, 32};
  const float sc = scales[lvl];
  const int sz = sizes[lvl];
  const float bx1 = px1 * sc, by1 = py1 * sc;
  const float w_unit = ((px2 - px1) * sc / 7.0f) * 0.5f;
  const float h_unit = ((py2 - py1) * sc / 7.0f) * 0.5f;
  if (lane < 14) {
    float x = bx1 + ((float)lane + 0.5f) * w_unit;
    int xf = (int)floorf(x);
    int x0 = min(max(xf, 0), sz - 1);
    int x1 = min(max(xf + 1, 0), sz - 1);
    wxa[lane] = (float)x1 - x;
    wxb[lane] = x - (float)x0;
    xo0[lane] = x0;
    xo1[lane] = x1;
  } else if (lane >= 32 && lane < 46) {
    const int i = lane - 32;
    float y = by1 + ((float)i + 0.5f) * h_unit;
    int yf = (int)floorf(y);
    int y0 = min(max(yf, 0), sz - 1);
    int y1 = min(max(yf + 1, 0), sz - 1);
    wya[i] = (float)y1 - y;
    wyb[i] = y - (float)y0;
    yo0[i] = y0 * sz;
    yo1[i] = y1 * sz;
  }
  __syncthreads();
  const float* fl = (lvl == 0) ? f0 : (lvl == 1) ? f1 : (lvl == 2) ? f2 : f3;
  const float* base = fl + (size_t)c * sz * sz;
  for (int oh = 0; oh < 7; ++oh) {
    float mm[7];
    #pragma unroll
    for (int ow = 0; ow < 7; ++ow) mm[ow] = -INFINITY;
    #pragma unroll
    for (int sy = 0; sy < 2; ++sy) {
      const int gy = oh * 2 + sy;
      const float* r0 = base + yo0[gy];
      const float* r1 = base + yo1[gy];
      const float wy0 = wya[gy], wy1 = wyb[gy];
      #pragma unroll
      for (int gx = 0; gx < 14; ++gx) {
        float v = wy0 * (wxa[gx] * r0[xo0[gx]] + wxb[gx] * r0[xo1[gx]]) +
                  wy1 * (wxa[gx] * r1[xo0[gx]] + wxb[gx] * r1[xo1[gx]]);
        mm[gx >> 1] = fmaxf(mm[gx >> 1], v);
      }
    }
    #pragma unroll
    for (int ow = 0; ow < 7; ++ow)
      out[((size_t)n * C_CH + c) * 49 + oh * 7 + ow] = mm[ow];
  }
}

extern "C" void kernel_launch(void* const* d_in, const int* in_sizes, int n_in,
                              void* d_out, int out_size, void* d_ws,
                              size_t ws_size, hipStream_t stream) {
  const float* f0 = (const float*)d_in[0];
  const float* f1 = (const float*)d_in[1];
  const float* f2 = (const float*)d_in[2];
  const float* f3 = (const float*)d_in[3];
  const float* props = (const float*)d_in[4];
  float* out = (float*)d_out;
  const int N = in_sizes[4] / 4;

  const size_t needed = (size_t)87040 * C_CH * sizeof(__hip_bfloat16);  // 44.6MB
  if (ws_size >= needed) {
    __hip_bfloat16* tf = (__hip_bfloat16*)d_ws;
    transpose_all<<<2720, 256, 0, stream>>>(f0, f1, f2, f3, tf);
    roi_bf16<<<2 * N, 512, 0, stream>>>((const unsigned short*)tf, props, out);
  } else {
    roi_fallback<<<dim3(N, 4), 64, 0, stream>>>(f0, f1, f2, f3, props, out);
  }
}

// Round 7
// 142.350 us; speedup vs baseline: 1.0124x; 1.0124x over previous
//
#include <hip/hip_runtime.h>
#include <hip/hip_bf16.h>
#include <math.h>

#define C_CH 256

typedef const __attribute__((address_space(1))) void* gas_t;
typedef __attribute__((address_space(3))) void* las_t;

// ---------------------------------------------------------------------------
// Transpose all 4 FPN levels from fp32 (C,H,W) to bf16 (H*W, C) in d_ws.
// R7 = exact R5 revert (proven best, 139.7 us total). R6's counted-vmcnt
// 2-tile pipeline regressed (+4.4): 32 KB LDS cut occupancy 8->5 blocks/CU
// and halved block count; cross-block TLP was already hiding the barrier
// drain (the m99/m100 lesson). Load phase: width-16 global_load_lds with the
// swizzle moved to the per-lane GLOBAL column (m173/T2) so LDS stays linear;
// store phase reads at exactly 2-way bank aliasing (free, m136).
// Traffic floor 133 MB -> ~21 us; this kernel runs at ~18-19 (stores overlap
// neighboring blocks' loads).
// ---------------------------------------------------------------------------
__global__ __launch_bounds__(256) void transpose_all(
    const float* __restrict__ f0, const float* __restrict__ f1,
    const float* __restrict__ f2, const float* __restrict__ f3,
    __hip_bfloat16* __restrict__ tf) {
  __shared__ float tile[64 * 64];  // linear, swizzled via global pre-permute
  const int b = blockIdx.x;  // 5440 total
  const float* src;
  int S, lg;
  size_t dstoff;
  int sb;
  if (b < 4096) {        // level0: 1024 sp-tiles x 4 cgroups
    src = f0; S = 65536; lg = 10; dstoff = 0;     sb = b;
  } else if (b < 5120) { // level1: 256 x 4
    src = f1; S = 16384; lg = 8;  dstoff = 65536; sb = b - 4096;
  } else if (b < 5376) { // level2: 64 x 4
    src = f2; S = 4096;  lg = 6;  dstoff = 81920; sb = b - 5120;
  } else {               // level3: 16 x 4
    src = f3; S = 1024;  lg = 4;  dstoff = 86016; sb = b - 5376;
  }
  const int nsp_m1 = (1 << lg) - 1;
  const int s0 = (sb & nsp_m1) * 64;
  const int c0 = (sb >> lg) * 64;

  const int t = threadIdx.x;
  const int lane = t & 63;
  const int wv = t >> 6;  // wave 0..3

  {  // load: one global_load_lds_dwordx4 per wave per j (fire-and-forget).
     // lane covers channel row c = 4*wv + 16*j + (lane>>4), physical 16B slot
     // s = lane&15; global column pre-swizzled by K = c>>2 = wv + 4*j
     // (wave-uniform), so LDS stays linear while the logical layout is
     // XOR-swizzled for the read phase.
    #pragma unroll
    for (int j = 0; j < 4; ++j) {
      const int c = 4 * wv + 16 * j + (lane >> 4);
      const int K = (wv + 4 * j) & 15;
      const int slot = (lane & 15) ^ K;
      const float* g = src + (size_t)(c0 + c) * S + s0 + slot * 4;
      float* l = &tile[(4 * wv + 16 * j) * 64];  // wave-uniform base
      __builtin_amdgcn_global_load_lds((gas_t)g, (las_t)l, 16, 0, 0);
    }
  }
  __syncthreads();  // drains vmcnt -> all DMA writes visible
  {  // store: gather 4 channels (2-way LDS, free), ushort4 stores, 128B runs
    const int spl = t >> 4;         // 0..15
    const int i16 = t & 15;
    const int c4 = i16 * 4;         // 0..60
    __hip_bfloat16* dst = tf + (dstoff + (size_t)s0) * C_CH + c0;
    #pragma unroll
    for (int j = 0; j < 4; ++j) {
      const int sp = spl + 16 * j;
      const int sl = sp >> 2;  // logical slot
      union { ushort4 u; __hip_bfloat16 h[4]; } p;
      #pragma unroll
      for (int k = 0; k < 4; ++k) {
        const int c = c4 + k;  // c>>2 == i16
        p.h[k] = __float2bfloat16(tile[c * 64 + ((sl ^ i16) << 2) + (sp & 3)]);
      }
      *(ushort4*)(dst + (size_t)sp * C_CH + c4) = p.u;
    }
  }
}

__device__ __forceinline__ float bfu(unsigned short s) {
  union { unsigned u; float f; } v;
  v.u = (unsigned)s << 16;
  return v.f;
}

// ---------------------------------------------------------------------------
// ROI Align + 2x2 max pool, transposed bf16 path. (R4 body, proven:
// channel-split 2x TLP -> 4 blocks/CU, 32 waves/CU = full occupancy.)
// ---------------------------------------------------------------------------
__global__ __launch_bounds__(512, 8) void roi_bf16(
    const unsigned short* __restrict__ tf,
    const float* __restrict__ proposals, float* __restrict__ out) {
  __shared__ int xo0[14], xo1[14], yo0[14], yo1[14];
  __shared__ float wxa[14], wxb[14], wya[14], wyb[14];
  __shared__ float obuf[49 * 128];  // 24.5 KB, XOR-swizzled 8-B slots

  const int n = blockIdx.x >> 1;
  const int half = blockIdx.x & 1;
  const int t = threadIdx.x;
  const int lane = t & 63;
  const int w = t >> 6;  // wave id 0..7

  const float px1 = proposals[n * 4 + 0];
  const float py1 = proposals[n * 4 + 1];
  const float px2 = proposals[n * 4 + 2];
  const float py2 = proposals[n * 4 + 3];
  float lt = 2.0f + log2f(sqrtf((px2 - px1) * (py2 - py1)) / 224.0f);
  int lvl = (int)floorf(lt);
  lvl = lvl < 0 ? 0 : (lvl > 3 ? 3 : lvl);

  const float scales[4] = {0.25f, 0.125f, 0.0625f, 0.03125f};
  const int sizes[4] = {256, 128, 64, 32};
  const int offs[4] = {0, 65536, 81920, 86016};
  const float sc = scales[lvl];
  const int sz = sizes[lvl];

  const float bx1 = px1 * sc, by1 = py1 * sc;
  const float w_unit = ((px2 - px1) * sc / 7.0f) * 0.5f;
  const float h_unit = ((py2 - py1) * sc / 7.0f) * 0.5f;

  if (t < 14) {
    const int i = t;
    float x = bx1 + ((float)i + 0.5f) * w_unit;
    int xf = (int)floorf(x);
    int x0 = min(max(xf, 0), sz - 1);
    int x1 = min(max(xf + 1, 0), sz - 1);
    wxa[i] = (float)x1 - x;  // matches ref incl. clipped extrapolation
    wxb[i] = x - (float)x0;
    xo0[i] = x0 * C_CH;
    xo1[i] = x1 * C_CH;
  } else if (t >= 64 && t < 78) {
    const int i = t - 64;
    float y = by1 + ((float)i + 0.5f) * h_unit;
    int yf = (int)floorf(y);
    int y0 = min(max(yf, 0), sz - 1);
    int y1 = min(max(yf + 1, 0), sz - 1);
    wya[i] = (float)y1 - y;
    wyb[i] = y - (float)y0;
    yo0[i] = y0 * sz * C_CH;
    yo1[i] = y1 * sz * C_CH;
  }
  __syncthreads();

  if (w < 7) {  // wave-uniform: waves 0-6 compute, wave 7 only helps store
    const int oh = w;
    const int gy0 = 2 * oh, gy1 = 2 * oh + 1;
    // lane covers channels half*128 + lane*2 (+0,+1)
    const unsigned short* base =
        tf + (size_t)offs[lvl] * C_CH + half * 128 + lane * 2;
    const unsigned short* r00 = base + yo0[gy0];
    const unsigned short* r01 = base + yo1[gy0];
    const unsigned short* r10 = base + yo0[gy1];
    const unsigned short* r11 = base + yo1[gy1];
    const float wy0a = wya[gy0], wy0b = wyb[gy0];
    const float wy1a = wya[gy1], wy1b = wyb[gy1];

    float mm[7][2];
    #pragma unroll
    for (int j = 0; j < 7; ++j) {
      mm[j][0] = -INFINITY;
      mm[j][1] = -INFINITY;
    }

    // Software-pipelined gather: prefetch gx+1 while computing gx.
    ushort2 nA0, nA1, nB0, nB1, nC0, nC1, nD0, nD1;
    {
      const int xa = xo0[0], xb = xo1[0];
      nA0 = *(const ushort2*)(r00 + xa);
      nA1 = *(const ushort2*)(r00 + xb);
      nB0 = *(const ushort2*)(r01 + xa);
      nB1 = *(const ushort2*)(r01 + xb);
      nC0 = *(const ushort2*)(r10 + xa);
      nC1 = *(const ushort2*)(r10 + xb);
      nD0 = *(const ushort2*)(r11 + xa);
      nD1 = *(const ushort2*)(r11 + xb);
    }
    #pragma unroll
    for (int gx = 0; gx < 14; ++gx) {
      const ushort2 A0 = nA0, A1 = nA1, B0 = nB0, B1 = nB1;
      const ushort2 C0 = nC0, C1 = nC1, D0 = nD0, D1 = nD1;
      if (gx < 13) {  // compile-time (fully unrolled)
        const int xa = xo0[gx + 1], xb = xo1[gx + 1];
        nA0 = *(const ushort2*)(r00 + xa);
        nA1 = *(const ushort2*)(r00 + xb);
        nB0 = *(const ushort2*)(r01 + xa);
        nB1 = *(const ushort2*)(r01 + xb);
        nC0 = *(const ushort2*)(r10 + xa);
        nC1 = *(const ushort2*)(r10 + xb);
        nD0 = *(const ushort2*)(r11 + xa);
        nD1 = *(const ushort2*)(r11 + xb);
      }
      const float fa = wxa[gx], fb = wxb[gx];
      const int j = gx >> 1;
      const unsigned short* a0 = (const unsigned short*)&A0;
      const unsigned short* a1 = (const unsigned short*)&A1;
      const unsigned short* b0 = (const unsigned short*)&B0;
      const unsigned short* b1 = (const unsigned short*)&B1;
      const unsigned short* c0 = (const unsigned short*)&C0;
      const unsigned short* c1 = (const unsigned short*)&C1;
      const unsigned short* d0 = (const unsigned short*)&D0;
      const unsigned short* d1 = (const unsigned short*)&D1;
      #pragma unroll
      for (int k = 0; k < 2; ++k) {
        const float h00 = fa * bfu(a0[k]) + fb * bfu(a1[k]);
        const float h01 = fa * bfu(b0[k]) + fb * bfu(b1[k]);
        const float va = wy0a * h00 + wy0b * h01;
        const float h10 = fa * bfu(c0[k]) + fb * bfu(c1[k]);
        const float h11 = fa * bfu(d0[k]) + fb * bfu(d1[k]);
        const float vb = wy1a * h10 + wy1b * h11;
        mm[j][k] = fmaxf(mm[j][k], fmaxf(va, vb));
      }
    }

    // Stage: obuf row p = oh*7+ow, 8-B slot (lane^p)&63 holds local channels
    // (2*lane, 2*lane+1). XOR keeps both write (float2, permutation -> exact
    // 2-way, free) and the epilogue's p-striding reads spread across banks.
    #pragma unroll
    for (int ow = 0; ow < 7; ++ow) {
      const int p = oh * 7 + ow;
      float2 v = make_float2(mm[ow][0], mm[ow][1]);
      *(float2*)&obuf[p * 128 + ((lane ^ p) & 63) * 2] = v;
    }
  }
  __syncthreads();

  // Contiguous coalesced block store of this half's 25 KB:
  // out[n*12544 + half*6272 + i], i = c_local*49 + p.
  float* ob = out + (size_t)n * (C_CH * 49) + half * (128 * 49);
  for (int i = t; i < 128 * 49; i += 512) {
    const unsigned cl = (unsigned)i / 49u;
    const unsigned p = (unsigned)i - cl * 49u;
    const unsigned q = ((cl >> 1) ^ p) & 63u;
    ob[i] = obuf[p * 128 + q * 2 + (cl & 1)];
  }
}

// ---------------------------------------------------------------------------
// Fallback (no workspace): direct (C,H,W) reads. Correctness-only path.
// ---------------------------------------------------------------------------
__global__ __launch_bounds__(64) void roi_fallback(
    const float* __restrict__ f0, const float* __restrict__ f1,
    const float* __restrict__ f2, const float* __restrict__ f3,
    const float* __restrict__ proposals, float* __restrict__ out) {
  __shared__ int xo0[14], xo1[14], yo0[14], yo1[14];
  __shared__ float wxa[14], wxb[14], wya[14], wyb[14];
  const int n = blockIdx.x;
  const int cblk = blockIdx.y;
  const int lane = threadIdx.x;
  const int c = cblk * 64 + lane;
  const float px1 = proposals[n * 4 + 0];
  const float py1 = proposals[n * 4 + 1];
  const float px2 = proposals[n * 4 + 2];
  const float py2 = proposals[n * 4 + 3];
  float lt = 2.0f + log2f(sqrtf((px2 - px1) * (py2 - py1)) / 224.0f);
  int lvl = (int)floorf(lt);
  lvl = lvl < 0 ? 0 : (lvl > 3 ? 3 : lvl);
  const float scales[4] = {0.25f, 0.125f, 0.0625f, 0.03125f};
  const int sizes[4] = {256, 128, 64, 32};
  const float sc = scales[lvl];
  const int sz = sizes[lvl];
  const float bx1 = px1 * sc, by1 = py1 * sc;
  const float w_unit = ((px2 - px1) * sc / 7.0f) * 0.5f;
  const float h_unit = ((py2 - py1) * sc / 7.0f) * 0.5f;
  if (lane < 14) {
    float x = bx1 + ((float)lane + 0.5f) * w_unit;
    int xf = (int)floorf(x);
    int x0 = min(max(xf, 0), sz - 1);
    int x1 = min(max(xf + 1, 0), sz - 1);
    wxa[lane] = (float)x1 - x;
    wxb[lane] = x - (float)x0;
    xo0[lane] = x0;
    xo1[lane] = x1;
  } else if (lane >= 32 && lane < 46) {
    const int i = lane - 32;
    float y = by1 + ((float)i + 0.5f) * h_unit;
    int yf = (int)floorf(y);
    int y0 = min(max(yf, 0), sz - 1);
    int y1 = min(max(yf + 1, 0), sz - 1);
    wya[i] = (float)y1 - y;
    wyb[i] = y - (float)y0;
    yo0[i] = y0 * sz;
    yo1[i] = y1 * sz;
  }
  __syncthreads();
  const float* fl = (lvl == 0) ? f0 : (lvl == 1) ? f1 : (lvl == 2) ? f2 : f3;
  const float* base = fl + (size_t)c * sz * sz;
  for (int oh = 0; oh < 7; ++oh) {
    float mm[7];
    #pragma unroll
    for (int ow = 0; ow < 7; ++ow) mm[ow] = -INFINITY;
    #pragma unroll
    for (int sy = 0; sy < 2; ++sy) {
      const int gy = oh * 2 + sy;
      const float* r0 = base + yo0[gy];
      const float* r1 = base + yo1[gy];
      const float wy0 = wya[gy], wy1 = wyb[gy];
      #pragma unroll
      for (int gx = 0; gx < 14; ++gx) {
        float v = wy0 * (wxa[gx] * r0[xo0[gx]] + wxb[gx] * r0[xo1[gx]]) +
                  wy1 * (wxa[gx] * r1[xo0[gx]] + wxb[gx] * r1[xo1[gx]]);
        mm[gx >> 1] = fmaxf(mm[gx >> 1], v);
      }
    }
    #pragma unroll
    for (int ow = 0; ow < 7; ++ow)
      out[((size_t)n * C_CH + c) * 49 + oh * 7 + ow] = mm[ow];
  }
}

extern "C" void kernel_launch(void* const* d_in, const int* in_sizes, int n_in,
                              void* d_out, int out_size, void* d_ws,
                              size_t ws_size, hipStream_t stream) {
  const float* f0 = (const float*)d_in[0];
  const float* f1 = (const float*)d_in[1];
  const float* f2 = (const float*)d_in[2];
  const float* f3 = (const float*)d_in[3];
  const float* props = (const float*)d_in[4];
  float* out = (float*)d_out;
  const int N = in_sizes[4] / 4;

  const size_t needed = (size_t)87040 * C_CH * sizeof(__hip_bfloat16);  // 44.6MB
  if (ws_size >= needed) {
    __hip_bfloat16* tf = (__hip_bfloat16*)d_ws;
    transpose_all<<<5440, 256, 0, stream>>>(f0, f1, f2, f3, tf);
    roi_bf16<<<2 * N, 512, 0, stream>>>((const unsigned short*)tf, props, out);
  } else {
    roi_fallback<<<dim3(N, 4), 64, 0, stream>>>(f0, f1, f2, f3, props, out);
  }
}